// Round 1
// baseline (125.951 us; speedup 1.0000x reference)
//
#include <hip/hip_runtime.h>
#include <math.h>

#define B_ 4
#define N_ 256
#define DE_ 128
#define DV_ 64
#define EPS_ 1e-5f

// ---------------- workspace layout (float offsets) ----------------
#define OFF_ETA   0
#define OFF_G     64
#define OFF_MR    128
#define OFF_MI    192
#define OFF_KER   256
#define OFF_KEI   (OFF_KER + N_*DV_)
#define OFF_LOGV  (OFF_KEI + N_*DV_)
#define OFF_INV   (OFF_LOGV + N_*DV_)
#define OFF_QR    (OFF_INV + N_*DV_)
#define OFF_QI    (OFF_QR + B_*N_*DV_)
#define OFF_KR    (OFF_QI + B_*N_*DV_)
#define OFF_KI    (OFF_KR + B_*N_*DV_)
#define OFF_VR    (OFF_KI + B_*N_*DV_)
#define OFF_VI    (OFF_VR + B_*N_*DV_)
#define OFF_PPR   (OFF_VI + B_*N_*DV_)
#define OFF_PPI   (OFF_PPR + B_*N_*DV_)
// total floats = OFF_PPI + B_*N_*DV_ = 590080  (~2.36 MB)

// ---------------- output layout (float offsets, concat in return order) ----
#define OUT_EL    0                               // est_latent (B,2,N,DV)
#define OUT_OUT   (B_*2*N_*DV_)                   // out        (B,2,N,DE)
#define OUT_QIJ   (OUT_OUT + B_*2*N_*DE_)         // Qij        (B,N,N,DV)
#define OUT_ZHAT  (OUT_QIJ + B_*N_*N_*DV_)        // Zhat       (B,2,N,N,DV)
#define OUT_LAMH  (OUT_ZHAT + (size_t)B_*2*N_*N_*DV_) // lambda_h (2,DV)

// =====================================================================
// Kernel A: per-delta tables (Ker, Kei, logVij, 1/(Vij+lamGa)) and per-d
// constants (eta, g, mr, mi) + lambda_h output.
// dt depends only on delta = i-j  (t = arange(N+1)*0.01), so the (N,N,DV)
// kernel tensors collapse to (N,DV) tables.
// =====================================================================
__global__ __launch_bounds__(DV_) void k_tables(
    const float* __restrict__ t,      // t_measure_all, row 0 used
    const float* __restrict__ lam1,   // (2,32) flat
    const float* __restrict__ lOm,    // (64,)
    const float* __restrict__ lGa,    // (64,)
    const float* __restrict__ eta_p,  // (64,)
    float* __restrict__ ws, float* __restrict__ out)
{
    const int delta = blockIdx.x;
    const int d = threadIdx.x;

    const float l0 = lam1[d & 31];
    const float re = -l0 * l0;
    const float im = (d < 32) ? lam1[32 + d] : -lam1[d];

    const float lo = lOm[d];
    const float lam_Om = lo * lo;
    const float lg = lGa[d];
    const float lam_Ga = lg * lg + EPS_;

    const float t0 = t[0];
    const float dt = t[delta] - t0;

    const float amp = expf(re * dt);
    const float ph  = im * dt;
    const int td = delta * DV_ + d;
    ws[OFF_KER + td] = amp * cosf(ph);
    ws[OFF_KEI + td] = amp * sinf(ph);

    const float e2  = expf(2.0f * re * dt);   // adt == dt for delta >= 0
    const float vij = lam_Ga * e2 + lam_Om * (e2 - 1.0f) / (2.0f * (re - EPS_));
    ws[OFF_LOGV + td] = logf(vij);
    ws[OFF_INV  + td] = 1.0f / (vij + lam_Ga);

    if (delta == 0) {
        const float eta = 1.0f / (1.0f + expf(-eta_p[d]));
        const float g   = 1.0f / (1.0f + expf(-eta));
        ws[OFF_ETA + d] = eta;
        ws[OFF_G   + d] = g;
        const float h  = t[1] - t0;
        const float ma = expf(re * h);
        ws[OFF_MR + d] = ma * cosf(im * h);
        ws[OFF_MI + d] = ma * sinf(im * h);
        out[OUT_LAMH + d]       = re;
        out[OUT_LAMH + DV_ + d] = im;
    }
}

// =====================================================================
// Kernel B: complex linear projections Q, K, V.
// One block per (b, n) row; thread = output channel d. Tiny GEMMs.
// =====================================================================
__global__ __launch_bounds__(DV_) void k_qkv(
    const float* __restrict__ Zq, const float* __restrict__ Zk, const float* __restrict__ Zv,
    const float* __restrict__ Wqr, const float* __restrict__ Wqi,
    const float* __restrict__ bqr, const float* __restrict__ bqi,
    const float* __restrict__ Wkr, const float* __restrict__ Wki,
    const float* __restrict__ bkr, const float* __restrict__ bki,
    const float* __restrict__ Wvr, const float* __restrict__ Wvi,
    const float* __restrict__ bvr, const float* __restrict__ bvi,
    float* __restrict__ ws)
{
    const int row = blockIdx.x;           // b*N + n
    const int b = row >> 8, n = row & (N_ - 1);
    const int d = threadIdx.x;

    __shared__ float x[6][DE_];
    const float* zq_r = Zq + ((size_t)(b*2+0)*N_ + n)*DE_;
    const float* zq_i = Zq + ((size_t)(b*2+1)*N_ + n)*DE_;
    const float* zk_r = Zk + ((size_t)(b*2+0)*N_ + n)*DE_;
    const float* zk_i = Zk + ((size_t)(b*2+1)*N_ + n)*DE_;
    const float* zv_r = Zv + ((size_t)(b*2+0)*N_ + n)*DE_;
    const float* zv_i = Zv + ((size_t)(b*2+1)*N_ + n)*DE_;
    for (int k = d; k < DE_; k += DV_) {
        x[0][k] = zq_r[k]; x[1][k] = zq_i[k];
        x[2][k] = zk_r[k]; x[3][k] = zk_i[k];
        x[4][k] = zv_r[k]; x[5][k] = zv_i[k];
    }
    __syncthreads();

    float aqr = bqr[d], aqi = bqi[d];
    float akr = bkr[d], aki = bki[d];
    float avr = bvr[d], avi = bvi[d];
    for (int k = 0; k < DE_; ++k) {
        float wr, wi;
        wr = Wqr[k*DV_ + d]; wi = Wqi[k*DV_ + d];
        aqr += x[0][k]*wr - x[1][k]*wi;
        aqi += x[0][k]*wi + x[1][k]*wr;
        wr = Wkr[k*DV_ + d]; wi = Wki[k*DV_ + d];
        akr += x[2][k]*wr - x[3][k]*wi;
        aki += x[2][k]*wi + x[3][k]*wr;
        wr = Wvr[k*DV_ + d]; wi = Wvi[k*DV_ + d];
        avr += x[4][k]*wr - x[5][k]*wi;
        avi += x[4][k]*wi + x[5][k]*wr;
    }
    const int o = row * DV_ + d;
    ws[OFF_QR + o] = aqr; ws[OFF_QI + o] = aqi;
    ws[OFF_KR + o] = akr; ws[OFF_KI + o] = aki;
    ws[OFF_VR + o] = avr; ws[OFF_VI + o] = avi;
}

// =====================================================================
// Kernel C: main pass. One block per (b, i). 4 waves; lane = d, waves
// stride over j <= i. Softmax over j per (b,i,d) with max-subtraction.
// Only the per-j log-term is stored in LDS (scores recomputed: cheap).
// =====================================================================
__global__ __launch_bounds__(256) void k_main(
    float* __restrict__ ws, float* __restrict__ out,
    const float* __restrict__ nf_p, const float* __restrict__ tau_p,
    const float* __restrict__ nu_p)
{
    const int row = blockIdx.x;               // b*N + i
    const int b = row >> 8, i = row & (N_ - 1);
    const int tid = (int)threadIdx.x;
    const int d = tid & 63;
    const int w = tid >> 6;                   // wave 0..3

    __shared__ float lb[N_];                  // log(nf + nu*dist_sum + EPS) per j
    __shared__ float redA[4][DV_];
    __shared__ float redB[4][DV_];

    const float nf    = nf_p[0];
    const float tau_a = fabsf(tau_p[0]);
    const float nu_a  = fabsf(nu_p[0]);

    const float* tabKer  = ws + OFF_KER;
    const float* tabKei  = ws + OFF_KEI;
    const float* tabLogV = ws + OFF_LOGV;
    const float* tabInv  = ws + OFF_INV;

    const float qr = ws[OFF_QR + row*DV_ + d];
    const float qi = ws[OFF_QI + row*DV_ + d];

    // ---- pass 1: dist_sum -> lb[j]; per-lane running max of scores ----
    float m_run = -3.0e38f;
    for (int j = w; j <= i; j += 4) {
        const int delta = i - j;
        const int td = delta*DV_ + d;
        const float ker = tabKer[td], kei = tabKei[td];
        const int kj = (b*N_ + j)*DV_ + d;
        const float kr = ws[OFF_KR + kj], ki = ws[OFF_KI + kj];
        const float rr = qr - (ker*kr - kei*ki);
        const float ri = qi - (ker*ki + kei*kr);
        float dsum = (rr*rr + ri*ri) * tabInv[td];
        #pragma unroll
        for (int off = 32; off; off >>= 1) dsum += __shfl_xor(dsum, off);
        const float l = logf(nf + nu_a*dsum + EPS_);
        if (d == 0) lb[j] = l;
        const float sc = -tau_a * (tabLogV[td] + l);
        m_run = fmaxf(m_run, sc);
    }
    redA[w][d] = m_run;
    __syncthreads();
    const float M = fmaxf(fmaxf(redA[0][d], redA[1][d]),
                          fmaxf(redA[2][d], redA[3][d]));

    // ---- pass 2: sum of exp (recompute scores from lb) ----
    float s_run = 0.0f;
    for (int j = w; j <= i; j += 4) {
        const int td = (i - j)*DV_ + d;
        const float sc = -tau_a * (tabLogV[td] + lb[j]);
        s_run += expf(sc - M);
    }
    redB[w][d] = s_run;
    __syncthreads();
    const float S = redB[0][d] + redB[1][d] + redB[2][d] + redB[3][d];
    const float inv = 1.0f / S;

    // ---- pass 3: outputs Qij, Zhat; accumulate est_v ----
    float evr = 0.0f, evi = 0.0f;
    float* qij  = out + OUT_QIJ  + (size_t)row * N_ * DV_;
    float* zr_o = out + OUT_ZHAT + ((size_t)(b*2+0)*N_ + i) * N_ * DV_;
    float* zi_o = out + OUT_ZHAT + ((size_t)(b*2+1)*N_ + i) * N_ * DV_;
    for (int j = w; j <= i; j += 4) {
        const int delta = i - j;
        const int td = delta*DV_ + d;
        const float sc = -tau_a * (tabLogV[td] + lb[j]);
        const float q = expf(sc - M) * inv;
        qij[j*DV_ + d] = q;
        const int vj = (b*N_ + j)*DV_ + d;
        const float vr = ws[OFF_VR + vj], vi = ws[OFF_VI + vj];
        const float ker = tabKer[td], kei = tabKei[td];
        const float zr = ker*vr - kei*vi;
        const float zi = ker*vi + kei*vr;
        zr_o[j*DV_ + d] = zr;
        zi_o[j*DV_ + d] = zi;
        evr += q * zr;
        evi += q * zi;
    }
    // zero-fill upper triangle (softmax of -inf -> 0; Zhat masked -> 0)
    for (int j = i + 1 + w; j < N_; j += 4) {
        qij[j*DV_ + d]  = 0.0f;
        zr_o[j*DV_ + d] = 0.0f;
        zi_o[j*DV_ + d] = 0.0f;
    }

    __syncthreads();   // everyone done reading redA/redB from earlier phases
    redA[w][d] = evr;
    redB[w][d] = evi;
    __syncthreads();
    if (w == 0) {
        const float Evr = redA[0][d] + redA[1][d] + redA[2][d] + redA[3][d];
        const float Evi = redB[0][d] + redB[1][d] + redB[2][d] + redB[3][d];
        const int ridx = row*DV_ + d;
        const float vr = ws[OFF_VR + ridx], vi = ws[OFF_VI + ridx];
        const float eta = ws[OFF_ETA + d], g = ws[OFF_G + d];
        const float elr = (1.0f - eta)*vr + g*Evr;
        const float eli = (1.0f - eta)*vi + g*Evi;
        out[OUT_EL + ((size_t)(b*2+0)*N_ + i)*DV_ + d] = elr;
        out[OUT_EL + ((size_t)(b*2+1)*N_ + i)*DV_ + d] = eli;
        const float mr = ws[OFF_MR + d], mi = ws[OFF_MI + d];
        ws[OFF_PPR + ridx] = mr*elr - mi*eli;
        ws[OFF_PPI + ridx] = mr*eli + mi*elr;
    }
}

// =====================================================================
// Kernel D: output projection  out = clin(ppr, ppi, Wp_r, Wp_i, bp).
// One block per (b,n); thread = output channel e (0..127).
// =====================================================================
__global__ __launch_bounds__(DE_) void k_proj(
    const float* __restrict__ ws,
    const float* __restrict__ Wpr, const float* __restrict__ Wpi,
    const float* __restrict__ bpr, const float* __restrict__ bpi,
    float* __restrict__ out)
{
    const int row = blockIdx.x;            // b*N + n
    const int b = row >> 8, n = row & (N_ - 1);
    const int e = threadIdx.x;

    __shared__ float pr[DV_], pim[DV_];
    if (e < DV_) {
        pr[e]  = ws[OFF_PPR + row*DV_ + e];
        pim[e] = ws[OFF_PPI + row*DV_ + e];
    }
    __syncthreads();

    float ar = bpr[e], ai = bpi[e];
    #pragma unroll 8
    for (int dd = 0; dd < DV_; ++dd) {
        const float wr = Wpr[dd*DE_ + e], wi = Wpi[dd*DE_ + e];
        const float r = pr[dd], im = pim[dd];
        ar += r*wr - im*wi;
        ai += r*wi + im*wr;
    }
    out[OUT_OUT + ((size_t)(b*2+0)*N_ + n)*DE_ + e] = ar;
    out[OUT_OUT + ((size_t)(b*2+1)*N_ + n)*DE_ + e] = ai;
}

// =====================================================================
extern "C" void kernel_launch(void* const* d_in, const int* in_sizes, int n_in,
                              void* d_out, int out_size, void* d_ws, size_t ws_size,
                              hipStream_t stream)
{
    const float* Zq   = (const float*)d_in[0];
    const float* Zk   = (const float*)d_in[1];
    const float* Zv   = (const float*)d_in[2];
    const float* t    = (const float*)d_in[3];
    const float* Wqr  = (const float*)d_in[4];
    const float* Wqi  = (const float*)d_in[5];
    const float* bqr  = (const float*)d_in[6];
    const float* bqi  = (const float*)d_in[7];
    const float* Wkr  = (const float*)d_in[8];
    const float* Wki  = (const float*)d_in[9];
    const float* bkr  = (const float*)d_in[10];
    const float* bki  = (const float*)d_in[11];
    const float* Wvr  = (const float*)d_in[12];
    const float* Wvi  = (const float*)d_in[13];
    const float* bvr  = (const float*)d_in[14];
    const float* bvi  = (const float*)d_in[15];
    const float* Wpr  = (const float*)d_in[16];
    const float* Wpi  = (const float*)d_in[17];
    const float* bpr  = (const float*)d_in[18];
    const float* bpi  = (const float*)d_in[19];
    const float* lam1 = (const float*)d_in[20];
    const float* lOm  = (const float*)d_in[21];
    const float* lGa  = (const float*)d_in[22];
    const float* nf   = (const float*)d_in[23];
    const float* tau  = (const float*)d_in[24];
    const float* nu   = (const float*)d_in[25];
    const float* etap = (const float*)d_in[26];

    float* ws  = (float*)d_ws;
    float* out = (float*)d_out;

    k_tables<<<N_, DV_, 0, stream>>>(t, lam1, lOm, lGa, etap, ws, out);
    k_qkv<<<B_*N_, DV_, 0, stream>>>(Zq, Zk, Zv,
                                     Wqr, Wqi, bqr, bqi,
                                     Wkr, Wki, bkr, bki,
                                     Wvr, Wvi, bvr, bvi, ws);
    k_main<<<B_*N_, 256, 0, stream>>>(ws, out, nf, tau, nu);
    k_proj<<<B_*N_, DE_, 0, stream>>>(ws, Wpr, Wpi, bpr, bpi, out);
}

// Round 2
// 72.941 us; speedup vs baseline: 1.7268x; 1.7268x over previous
//
#include <hip/hip_runtime.h>
#include <math.h>

#define B_ 4
#define N_ 256
#define DE_ 128
#define DV_ 64
#define EPS_ 1e-5f

typedef __attribute__((ext_vector_type(4))) float f32x4;

__device__ __forceinline__ f32x4 ld4(const float* p) { return *(const f32x4*)p; }
__device__ __forceinline__ void st4(float* p, f32x4 v) { *(f32x4*)p = v; }
__device__ __forceinline__ void nt4(float* p, f32x4 v) { __builtin_nontemporal_store(v, (f32x4*)p); }
__device__ __forceinline__ f32x4 exp4(f32x4 a) {
    f32x4 r; r[0]=expf(a[0]); r[1]=expf(a[1]); r[2]=expf(a[2]); r[3]=expf(a[3]); return r;
}
__device__ __forceinline__ f32x4 max4(f32x4 a, f32x4 b) {
    f32x4 r; r[0]=fmaxf(a[0],b[0]); r[1]=fmaxf(a[1],b[1]); r[2]=fmaxf(a[2],b[2]); r[3]=fmaxf(a[3],b[3]); return r;
}

// ---------------- workspace layout (float offsets) ----------------
#define OFF_ETA   0
#define OFF_G     64
#define OFF_MR    128
#define OFF_MI    192
#define OFF_KER   256
#define OFF_KEI   (OFF_KER + N_*DV_)
#define OFF_LOGV  (OFF_KEI + N_*DV_)
#define OFF_INV   (OFF_LOGV + N_*DV_)
#define OFF_QR    (OFF_INV + N_*DV_)
#define OFF_QI    (OFF_QR + B_*N_*DV_)
#define OFF_KR    (OFF_QI + B_*N_*DV_)
#define OFF_KI    (OFF_KR + B_*N_*DV_)
#define OFF_VR    (OFF_KI + B_*N_*DV_)
#define OFF_VI    (OFF_VR + B_*N_*DV_)

// ---------------- output layout (float offsets, concat in return order) ----
#define OUT_EL    0
#define OUT_OUT   (B_*2*N_*DV_)
#define OUT_QIJ   (OUT_OUT + B_*2*N_*DE_)
#define OUT_ZHAT  (OUT_QIJ + B_*N_*N_*DV_)
#define OUT_LAMH  (OUT_ZHAT + (size_t)B_*2*N_*N_*DV_)

// =====================================================================
// Kernel 1 (fused): blocks 0..1023 = QKV projections (k-split, 4 waves);
// blocks 1024..1087 = per-delta tables (4 deltas each).
// =====================================================================
__global__ __launch_bounds__(256) void k_pre(
    const float* __restrict__ Zq, const float* __restrict__ Zk, const float* __restrict__ Zv,
    const float* __restrict__ Wqr, const float* __restrict__ Wqi,
    const float* __restrict__ bqr, const float* __restrict__ bqi,
    const float* __restrict__ Wkr, const float* __restrict__ Wki,
    const float* __restrict__ bkr, const float* __restrict__ bki,
    const float* __restrict__ Wvr, const float* __restrict__ Wvi,
    const float* __restrict__ bvr, const float* __restrict__ bvi,
    const float* __restrict__ t,  const float* __restrict__ lam1,
    const float* __restrict__ lOm, const float* __restrict__ lGa,
    const float* __restrict__ eta_p,
    float* __restrict__ ws, float* __restrict__ out)
{
    const int tid = (int)threadIdx.x;

    if (blockIdx.x >= 1024) {
        // ---------------- tables branch ----------------
        const int idx = (int)blockIdx.x - 1024;
        const int w = tid >> 6;
        const int d = tid & 63;
        const int delta = idx * 4 + w;

        const float l0 = lam1[d & 31];
        const float re = -l0 * l0;
        const float im = (d < 32) ? lam1[32 + d] : -lam1[d];

        const float lo = lOm[d];
        const float lam_Om = lo * lo;
        const float lg_ = lGa[d];
        const float lam_Ga = lg_ * lg_ + EPS_;

        const float t0 = t[0];
        const float dt = t[delta] - t0;

        const float amp = expf(re * dt);
        const float ph  = im * dt;
        const int td = delta * DV_ + d;
        ws[OFF_KER + td] = amp * cosf(ph);
        ws[OFF_KEI + td] = amp * sinf(ph);

        const float e2  = expf(2.0f * re * dt);
        const float vij = lam_Ga * e2 + lam_Om * (e2 - 1.0f) / (2.0f * (re - EPS_));
        ws[OFF_LOGV + td] = logf(vij);
        ws[OFF_INV  + td] = 1.0f / (vij + lam_Ga);

        if (delta == 0) {
            const float eta = 1.0f / (1.0f + expf(-eta_p[d]));
            const float g   = 1.0f / (1.0f + expf(-eta));
            ws[OFF_ETA + d] = eta;
            ws[OFF_G   + d] = g;
            const float h  = t[1] - t0;
            const float ma = expf(re * h);
            ws[OFF_MR + d] = ma * cosf(im * h);
            ws[OFF_MI + d] = ma * sinf(im * h);
            out[OUT_LAMH + d]       = re;
            out[OUT_LAMH + DV_ + d] = im;
        }
        return;
    }

    // ---------------- QKV branch ----------------
    const int row = (int)blockIdx.x;        // b*N + n
    const int b = row >> 8, n = row & (N_ - 1);

    __shared__ float x[6][DE_];
    __shared__ float red[4][6][DV_];

    if (tid < DE_) {
        x[0][tid] = Zq[((size_t)(b*2+0)*N_ + n)*DE_ + tid];
        x[1][tid] = Zq[((size_t)(b*2+1)*N_ + n)*DE_ + tid];
        x[2][tid] = Zk[((size_t)(b*2+0)*N_ + n)*DE_ + tid];
        x[3][tid] = Zk[((size_t)(b*2+1)*N_ + n)*DE_ + tid];
        x[4][tid] = Zv[((size_t)(b*2+0)*N_ + n)*DE_ + tid];
        x[5][tid] = Zv[((size_t)(b*2+1)*N_ + n)*DE_ + tid];
    }
    __syncthreads();

    const int w = tid >> 6;                 // k-chunk: k in [32w, 32w+32)
    const int d = tid & 63;
    float aqr = 0.f, aqi = 0.f, akr = 0.f, aki = 0.f, avr = 0.f, avi = 0.f;
    const int k0 = w * 32;
    #pragma unroll 4
    for (int kk = 0; kk < 32; ++kk) {
        const int k = k0 + kk;
        const float xqr = x[0][k], xqi = x[1][k];
        const float xkr = x[2][k], xki = x[3][k];
        const float xvr = x[4][k], xvi = x[5][k];
        float wr, wi;
        wr = Wqr[k*DV_ + d]; wi = Wqi[k*DV_ + d];
        aqr += xqr*wr - xqi*wi; aqi += xqr*wi + xqi*wr;
        wr = Wkr[k*DV_ + d]; wi = Wki[k*DV_ + d];
        akr += xkr*wr - xki*wi; aki += xkr*wi + xki*wr;
        wr = Wvr[k*DV_ + d]; wi = Wvi[k*DV_ + d];
        avr += xvr*wr - xvi*wi; avi += xvr*wi + xvi*wr;
    }
    red[w][0][d] = aqr; red[w][1][d] = aqi;
    red[w][2][d] = akr; red[w][3][d] = aki;
    red[w][4][d] = avr; red[w][5][d] = avi;
    __syncthreads();

    if (tid < DV_) {
        const int o = row * DV_ + tid;
        ws[OFF_QR + o] = red[0][0][tid]+red[1][0][tid]+red[2][0][tid]+red[3][0][tid] + bqr[tid];
        ws[OFF_QI + o] = red[0][1][tid]+red[1][1][tid]+red[2][1][tid]+red[3][1][tid] + bqi[tid];
        ws[OFF_KR + o] = red[0][2][tid]+red[1][2][tid]+red[2][2][tid]+red[3][2][tid] + bkr[tid];
        ws[OFF_KI + o] = red[0][3][tid]+red[1][3][tid]+red[2][3][tid]+red[3][3][tid] + bki[tid];
        ws[OFF_VR + o] = red[0][4][tid]+red[1][4][tid]+red[2][4][tid]+red[3][4][tid] + bvr[tid];
        ws[OFF_VI + o] = red[0][5][tid]+red[1][5][tid]+red[2][5][tid]+red[3][5][tid] + bvi[tid];
    }
}

// =====================================================================
// Kernel 2: main pass + fused output projection.
// One block per (b,i). 4 waves. Each wave-iter covers 4 j-rows: lane l
// -> group g=l>>4 owns j=jb+g, lane-in-group q16=l&15 owns d-quad q16*4.
// Online softmax (no separate sum pass). float4 NT stores for Qij/Zhat.
// =====================================================================
__global__ __launch_bounds__(256) void k_main2(
    const float* __restrict__ ws, float* __restrict__ out,
    const float* __restrict__ Wpr, const float* __restrict__ Wpi,
    const float* __restrict__ bpr, const float* __restrict__ bpi,
    const float* __restrict__ nf_p, const float* __restrict__ tau_p,
    const float* __restrict__ nu_p)
{
    const int row = (int)blockIdx.x;          // b*N + i
    const int b = row >> 8, i = row & (N_ - 1);
    const int tid = (int)threadIdx.x;
    const int w = tid >> 6;
    const int l = tid & 63;
    const int g = l >> 4;                     // j sub-slot
    const int q16 = l & 15;                   // d-quad index
    const int dq = q16 * 4;

    __shared__ float lb[N_];
    __shared__ f32x4 redM[4][16];
    __shared__ f32x4 redS[4][16];
    __shared__ f32x4 redR[4][16];
    __shared__ f32x4 redI[4][16];
    __shared__ float ppr_s[DV_], ppi_s[DV_];

    const float nf    = nf_p[0];
    const float tau_a = fabsf(tau_p[0]);
    const float nu_a  = fabsf(nu_p[0]);

    const f32x4 qr4 = ld4(ws + OFF_QR + row*DV_ + dq);
    const f32x4 qi4 = ld4(ws + OFF_QI + row*DV_ + dq);

    // ---- pass 1: mahalanobis -> lb[j]; online softmax (m,s) over j per d ----
    f32x4 m4 = {-3.0e38f, -3.0e38f, -3.0e38f, -3.0e38f};
    f32x4 s4 = {0.f, 0.f, 0.f, 0.f};
    for (int jb = 4*w; jb <= i; jb += 16) {
        const int j = jb + g;
        const bool act = (j <= i);
        const int delta = act ? (i - j) : 0;
        const int td = delta*DV_ + dq;
        const f32x4 ker = ld4(ws + OFF_KER  + td);
        const f32x4 kei = ld4(ws + OFF_KEI  + td);
        const f32x4 vnv = ld4(ws + OFF_INV  + td);
        const f32x4 lgv = ld4(ws + OFF_LOGV + td);
        const int kj = (b*N_ + (act ? j : 0))*DV_ + dq;
        const f32x4 kr = ld4(ws + OFF_KR + kj);
        const f32x4 ki = ld4(ws + OFF_KI + kj);
        const f32x4 rr = qr4 - (ker*kr - kei*ki);
        const f32x4 ri = qi4 - (ker*ki + kei*kr);
        const f32x4 mah = (rr*rr + ri*ri) * vnv;
        float ds = mah[0] + mah[1] + mah[2] + mah[3];
        ds += __shfl_xor(ds, 1);
        ds += __shfl_xor(ds, 2);
        ds += __shfl_xor(ds, 4);
        ds += __shfl_xor(ds, 8);
        const float lg = logf(nf + nu_a*ds + EPS_);
        if (act) {
            if (q16 == 0) lb[j] = lg;
            const f32x4 sc = (-tau_a) * (lgv + lg);
            const f32x4 mn = max4(m4, sc);
            s4 = s4 * exp4(m4 - mn) + exp4(sc - mn);
            m4 = mn;
        }
    }
    // combine across the 4 g-slots (lanes l, l^16, l^32, l^48)
    #pragma unroll
    for (int mask = 16; mask <= 32; mask <<= 1) {
        f32x4 mo, so;
        #pragma unroll
        for (int c = 0; c < 4; ++c) { mo[c] = __shfl_xor(m4[c], mask); so[c] = __shfl_xor(s4[c], mask); }
        const f32x4 mn = max4(m4, mo);
        s4 = s4 * exp4(m4 - mn) + so * exp4(mo - mn);
        m4 = mn;
    }
    if (g == 0) { redM[w][q16] = m4; redS[w][q16] = s4; }
    __syncthreads();
    f32x4 M = redM[0][q16], S = redS[0][q16];
    #pragma unroll
    for (int w2 = 1; w2 < 4; ++w2) {
        const f32x4 mo = redM[w2][q16], so = redS[w2][q16];
        const f32x4 mn = max4(M, mo);
        S = S * exp4(M - mn) + so * exp4(mo - mn);
        M = mn;
    }
    const f32x4 one = {1.f, 1.f, 1.f, 1.f};
    const f32x4 inv = one / S;

    // ---- pass 2: Qij / Zhat writes + est_v accumulation ----
    f32x4 evr = {0.f,0.f,0.f,0.f}, evi = {0.f,0.f,0.f,0.f};
    float* qij  = out + OUT_QIJ + (size_t)row * N_ * DV_;
    float* zro  = out + OUT_ZHAT + ((size_t)(b*2+0)*N_ + i) * N_ * DV_;
    float* zio  = out + OUT_ZHAT + ((size_t)(b*2+1)*N_ + i) * N_ * DV_;
    const f32x4 z4 = {0.f,0.f,0.f,0.f};
    for (int jb = 4*w; jb < N_; jb += 16) {
        const int j = jb + g;
        const int o = j*DV_ + dq;
        if (j <= i) {
            const int td = (i - j)*DV_ + dq;
            const f32x4 lgv = ld4(ws + OFF_LOGV + td);
            const f32x4 ker = ld4(ws + OFF_KER + td);
            const f32x4 kei = ld4(ws + OFF_KEI + td);
            const float lg = lb[j];
            const f32x4 q4 = exp4((-tau_a)*(lgv + lg) - M) * inv;
            nt4(qij + o, q4);
            const int vj = (b*N_ + j)*DV_ + dq;
            const f32x4 vr = ld4(ws + OFF_VR + vj);
            const f32x4 vi = ld4(ws + OFF_VI + vj);
            const f32x4 zr = ker*vr - kei*vi;
            const f32x4 zi = ker*vi + kei*vr;
            nt4(zro + o, zr);
            nt4(zio + o, zi);
            evr += q4 * zr;
            evi += q4 * zi;
        } else {
            nt4(qij + o, z4);
            nt4(zro + o, z4);
            nt4(zio + o, z4);
        }
    }
    #pragma unroll
    for (int mask = 16; mask <= 32; mask <<= 1) {
        #pragma unroll
        for (int c = 0; c < 4; ++c) {
            evr[c] += __shfl_xor(evr[c], mask);
            evi[c] += __shfl_xor(evi[c], mask);
        }
    }
    if (g == 0) { redR[w][q16] = evr; redI[w][q16] = evi; }
    __syncthreads();

    // ---- epilogue: est_latent + pp (16 lanes cover DV=64 as quads) ----
    if (tid < 16) {
        const f32x4 Evr = redR[0][tid] + redR[1][tid] + redR[2][tid] + redR[3][tid];
        const f32x4 Evi = redI[0][tid] + redI[1][tid] + redI[2][tid] + redI[3][tid];
        const int dq2 = tid * 4;
        const f32x4 vr  = ld4(ws + OFF_VR + row*DV_ + dq2);
        const f32x4 vi  = ld4(ws + OFF_VI + row*DV_ + dq2);
        const f32x4 eta = ld4(ws + OFF_ETA + dq2);
        const f32x4 gg  = ld4(ws + OFF_G + dq2);
        const f32x4 elr = (1.0f - eta)*vr + gg*Evr;
        const f32x4 eli = (1.0f - eta)*vi + gg*Evi;
        st4(out + OUT_EL + ((size_t)(b*2+0)*N_ + i)*DV_ + dq2, elr);
        st4(out + OUT_EL + ((size_t)(b*2+1)*N_ + i)*DV_ + dq2, eli);
        const f32x4 mr = ld4(ws + OFF_MR + dq2);
        const f32x4 mi = ld4(ws + OFF_MI + dq2);
        st4(ppr_s + dq2, mr*elr - mi*eli);
        st4(ppi_s + dq2, mr*eli + mi*elr);
    }
    __syncthreads();

    // ---- fused output projection (DE=128 channels, threads 0..127) ----
    if (tid < DE_) {
        const int e = tid;
        float ar = bpr[e], ai = bpi[e];
        #pragma unroll 8
        for (int dd = 0; dd < DV_; ++dd) {
            const float wr = Wpr[dd*DE_ + e], wi = Wpi[dd*DE_ + e];
            const float r = ppr_s[dd], im = ppi_s[dd];
            ar += r*wr - im*wi;
            ai += r*wi + im*wr;
        }
        out[OUT_OUT + ((size_t)(b*2+0)*N_ + i)*DE_ + e] = ar;
        out[OUT_OUT + ((size_t)(b*2+1)*N_ + i)*DE_ + e] = ai;
    }
}

// =====================================================================
extern "C" void kernel_launch(void* const* d_in, const int* in_sizes, int n_in,
                              void* d_out, int out_size, void* d_ws, size_t ws_size,
                              hipStream_t stream)
{
    const float* Zq   = (const float*)d_in[0];
    const float* Zk   = (const float*)d_in[1];
    const float* Zv   = (const float*)d_in[2];
    const float* t    = (const float*)d_in[3];
    const float* Wqr  = (const float*)d_in[4];
    const float* Wqi  = (const float*)d_in[5];
    const float* bqr  = (const float*)d_in[6];
    const float* bqi  = (const float*)d_in[7];
    const float* Wkr  = (const float*)d_in[8];
    const float* Wki  = (const float*)d_in[9];
    const float* bkr  = (const float*)d_in[10];
    const float* bki  = (const float*)d_in[11];
    const float* Wvr  = (const float*)d_in[12];
    const float* Wvi  = (const float*)d_in[13];
    const float* bvr  = (const float*)d_in[14];
    const float* bvi  = (const float*)d_in[15];
    const float* Wpr  = (const float*)d_in[16];
    const float* Wpi  = (const float*)d_in[17];
    const float* bpr  = (const float*)d_in[18];
    const float* bpi  = (const float*)d_in[19];
    const float* lam1 = (const float*)d_in[20];
    const float* lOm  = (const float*)d_in[21];
    const float* lGa  = (const float*)d_in[22];
    const float* nf   = (const float*)d_in[23];
    const float* tau  = (const float*)d_in[24];
    const float* nu   = (const float*)d_in[25];
    const float* etap = (const float*)d_in[26];

    float* ws  = (float*)d_ws;
    float* out = (float*)d_out;

    k_pre<<<1024 + 64, 256, 0, stream>>>(Zq, Zk, Zv,
                                         Wqr, Wqi, bqr, bqi,
                                         Wkr, Wki, bkr, bki,
                                         Wvr, Wvi, bvr, bvi,
                                         t, lam1, lOm, lGa, etap, ws, out);
    k_main2<<<B_*N_, 256, 0, stream>>>(ws, out, Wpr, Wpi, bpr, bpi, nf, tau, nu);
}